// Round 11
// baseline (386.574 us; speedup 1.0000x reference)
//
#include <hip/hip_runtime.h>

#define NTOT 131072   // B*T = 16*8192
#define KCB  512
#define DIM  64

__device__ __forceinline__ float wave_sum(float v) {
#pragma unroll
  for (int off = 32; off; off >>= 1) v += __shfl_xor(v, off, 64);
  return v;
}

// ---------------------------------------------------------------------------
// K1 DIAGNOSTIC BUILD (round 11): identical to the 239us R6 kernel, but the
// tile loop runs TWICE (rep=0,1). Rep 1 recomputes and re-stores dist/enc
// (bit-identical, idempotent, deterministic); idx/cnt/dw only on rep 0.
// Purpose: push this dispatch above the harness's ~330us fill kernels so the
// top-5 counter table finally shows k_dist's VALUBusy / WRITE_SIZE /
// FETCH_SIZE / Occupancy / VGPR count. Perf is expected to be ~2x k_dist.
// ---------------------------------------------------------------------------
__global__ __launch_bounds__(512, 2) void k_dist(
    const float* __restrict__ x_g,      // [D][N]
    const float* __restrict__ emb_g,    // [K][D]
    float* __restrict__ dist_out,       // [N][K]
    float* __restrict__ enc_out,        // [N][K]
    int* __restrict__ idx_out,          // [N]
    unsigned* __restrict__ cnt_g,       // [K]
    float* __restrict__ dw_g)           // [K][D]
{
  __shared__ __align__(16) float embt[DIM][KCB];   // -2*emb[k][d] at [d][k]
  __shared__ __align__(16) float xls[8][8][65];    // per-wave 8 rows, padded
  __shared__ unsigned lcnt[KCB];

  const int t = threadIdx.x;
  const int lane = t & 63;
  const int w = t >> 6;

  lcnt[t] = 0u;

  // ---- stage embedding (once): thread t owns code row t
  {
    const float* er = emb_g + t * DIM;
#pragma unroll
    for (int d0 = 0; d0 < DIM; d0 += 4) {
      const float4 e = *reinterpret_cast<const float4*>(er + d0);
      embt[d0 + 0][t] = -2.f * e.x;
      embt[d0 + 1][t] = -2.f * e.y;
      embt[d0 + 2][t] = -2.f * e.z;
      embt[d0 + 3][t] = -2.f * e.w;
    }
  }
  __syncthreads();   // the only block-wide barrier (until the final one)

  // ---- per-lane |emb|^2 for its 8 k's: sq = 0.25 * sum((-2e)^2)
  float ebr[8] = {0.f, 0.f, 0.f, 0.f, 0.f, 0.f, 0.f, 0.f};
  for (int d = 0; d < DIM; ++d) {
    const float4 a = *reinterpret_cast<const float4*>(&embt[d][4 * lane]);
    const float4 b = *reinterpret_cast<const float4*>(&embt[d][256 + 4 * lane]);
    ebr[0] = fmaf(a.x, a.x, ebr[0]); ebr[1] = fmaf(a.y, a.y, ebr[1]);
    ebr[2] = fmaf(a.z, a.z, ebr[2]); ebr[3] = fmaf(a.w, a.w, ebr[3]);
    ebr[4] = fmaf(b.x, b.x, ebr[4]); ebr[5] = fmaf(b.y, b.y, ebr[5]);
    ebr[6] = fmaf(b.z, b.z, ebr[6]); ebr[7] = fmaf(b.w, b.w, ebr[7]);
  }
#pragma unroll
  for (int j = 0; j < 8; ++j) ebr[j] *= 0.25f;

  const int nb = blockIdx.x * 512;
  const int r_own = lane & 7;           // this lane's row within wave tile
  const int dgc   = lane >> 3;          // d-chunk 0..7

  for (int rep = 0; rep < 2; ++rep) {   // DIAGNOSTIC: run the loop twice
  for (int tt = 0; tt < 8; ++tt) {
    const int n0w = nb + tt * 64 + w * 8;   // wave's 8 rows

    // fence: prior iteration's xls reads retire before overwrite
    asm volatile("" ::: "memory");

    // ---- wave-private x load: lane loads row r_own, d-chunk dgc (8 vals)
    float xv[8];
#pragma unroll
    for (int j = 0; j < 8; ++j)
      xv[j] = x_g[(size_t)(dgc * 8 + j) * NTOT + n0w + r_own];
#pragma unroll
    for (int j = 0; j < 8; ++j)
      xls[w][r_own][dgc * 8 + j] = xv[j];

    // fence: staging writes ordered before reads (wave-synchronous LDS)
    asm volatile("" ::: "memory");

    // ---- |x|^2 for row r_own: partial over chunk, butterfly over chunks
    float ps = 0.f;
#pragma unroll
    for (int j = 0; j < 8; ++j) ps = fmaf(xv[j], xv[j], ps);
    ps += __shfl_xor(ps, 8, 64);
    ps += __shfl_xor(ps, 16, 64);
    ps += __shfl_xor(ps, 32, 64);       // lane r holds |x[row r]|^2 (r = lane&7)

    // ---- transpose via LDS: lane l holds x[row r][d=l]
    float xr[8];
#pragma unroll
    for (int r = 0; r < 8; ++r) xr[r] = xls[w][r][lane];

    // ---- accumulators init with |e_k|^2
    float acc[8][8];
#pragma unroll
    for (int r = 0; r < 8; ++r)
#pragma unroll
      for (int j = 0; j < 8; ++j) acc[r][j] = ebr[j];

    // ---- GEMM: acc[r][j] += x[r][d] * (-2 e[k_j][d])
#pragma unroll 2
    for (int d = 0; d < DIM; ++d) {
      const float4 e0 = *reinterpret_cast<const float4*>(&embt[d][4 * lane]);
      const float4 e1 = *reinterpret_cast<const float4*>(&embt[d][256 + 4 * lane]);
#pragma unroll
      for (int r = 0; r < 8; ++r) {
        const float s = __uint_as_float(
            __builtin_amdgcn_readlane(__float_as_uint(xr[r]), d));
        acc[r][0] = fmaf(s, e0.x, acc[r][0]);
        acc[r][1] = fmaf(s, e0.y, acc[r][1]);
        acc[r][2] = fmaf(s, e0.z, acc[r][2]);
        acc[r][3] = fmaf(s, e0.w, acc[r][3]);
        acc[r][4] = fmaf(s, e1.x, acc[r][4]);
        acc[r][5] = fmaf(s, e1.y, acc[r][5]);
        acc[r][6] = fmaf(s, e1.z, acc[r][6]);
        acc[r][7] = fmaf(s, e1.w, acc[r][7]);
      }
    }

    // ---- epilogue per row: +|x|^2, argmin, float4 stores, idx/cnt/dw
#pragma unroll
    for (int r = 0; r < 8; ++r) {
      const int nr = n0w + r;
      const float xs = __uint_as_float(
          __builtin_amdgcn_readlane(__float_as_uint(ps), r));
      float dv[8];
#pragma unroll
      for (int j = 0; j < 8; ++j) dv[j] = acc[r][j] + xs;

      // argmin, first-min tie-break: pack (dist_bits, k); dists > 0
      unsigned long long best = ~0ull;
#pragma unroll
      for (int j = 0; j < 8; ++j) {
        const unsigned kk = (j < 4) ? (unsigned)(4 * lane + j)
                                    : (unsigned)(256 + 4 * lane + (j - 4));
        const unsigned long long pk =
            ((unsigned long long)__float_as_uint(dv[j]) << 32) | kk;
        best = pk < best ? pk : best;
      }
#pragma unroll
      for (int off = 32; off; off >>= 1) {
        const unsigned long long o = __shfl_xor(best, off, 64);
        best = o < best ? o : best;
      }
      const int kmin = (int)(best & 0xFFFFFFFFull);

      float* dp = dist_out + (size_t)nr * KCB + 4 * lane;
      float4 q;
      q.x = dv[0]; q.y = dv[1]; q.z = dv[2]; q.w = dv[3];
      *reinterpret_cast<float4*>(dp) = q;
      q.x = dv[4]; q.y = dv[5]; q.z = dv[6]; q.w = dv[7];
      *reinterpret_cast<float4*>(dp + 256) = q;

      float* ep = enc_out + (size_t)nr * KCB + 4 * lane;
      const int k0 = 4 * lane;
      float4 z;
      z.x = (kmin == k0)     ? 1.f : 0.f;
      z.y = (kmin == k0 + 1) ? 1.f : 0.f;
      z.z = (kmin == k0 + 2) ? 1.f : 0.f;
      z.w = (kmin == k0 + 3) ? 1.f : 0.f;
      *reinterpret_cast<float4*>(ep) = z;
      z.x = (kmin == 256 + k0)     ? 1.f : 0.f;
      z.y = (kmin == 256 + k0 + 1) ? 1.f : 0.f;
      z.z = (kmin == 256 + k0 + 2) ? 1.f : 0.f;
      z.w = (kmin == 256 + k0 + 3) ? 1.f : 0.f;
      *reinterpret_cast<float4*>(ep + 256) = z;

      if (rep == 0) {
        if (lane == 0) {
          idx_out[nr] = kmin;
          atomicAdd(&lcnt[kmin], 1u);
        }
        // dw[kmin][d] += x[nr][d], d = lane
        unsafeAtomicAdd(dw_g + ((size_t)kmin << 6) + lane, xr[r]);
      }
    }
  }
  }

  __syncthreads();
  if (lcnt[t]) atomicAdd(&cnt_g[t], lcnt[t]);
}

// ---------------------------------------------------------------------------
// K3: cluster EMA + laplace + new_emb + perplexity (1 block, 512 threads)
// ---------------------------------------------------------------------------
__global__ __launch_bounds__(512, 1) void k_final(
    const float* __restrict__ ema_w, const float* __restrict__ ema_cs,
    const unsigned* __restrict__ cnt, const float* __restrict__ dw,
    float* __restrict__ nemb, float* __restrict__ out)
{
  __shared__ float red[8];
  __shared__ float bc;
  const int t = threadIdx.x;
  const int lane = t & 63, w = t >> 6;

  const float c = (float)cnt[t];
  const float craw = ema_cs[t] * 0.99f + 0.01f * c;

  float s = wave_sum(craw);
  if (lane == 0) red[w] = s;
  __syncthreads();
  if (t == 0) {
    float a = 0.f;
#pragma unroll
    for (int i = 0; i < 8; ++i) a += red[i];
    bc = a;
  }
  __syncthreads();
  const float n = bc;
  const float clus = (craw + 1e-5f) / (n + 512.f * 1e-5f) * n;

  const float4* wr = reinterpret_cast<const float4*>(ema_w + t * 64);
  const float4* dr = reinterpret_cast<const float4*>(dw + t * 64);
  float4* nr = reinterpret_cast<float4*>(nemb + t * 64);
#pragma unroll
  for (int q = 0; q < 16; ++q) {
    const float4 wv = wr[q], dv = dr[q];
    float4 o;
    o.x = (wv.x * 0.99f + 0.01f * dv.x) / clus;
    o.y = (wv.y * 0.99f + 0.01f * dv.y) / clus;
    o.z = (wv.z * 0.99f + 0.01f * dv.z) / clus;
    o.w = (wv.w * 0.99f + 0.01f * dv.w) / clus;
    nr[q] = o;
  }

  const float p = c * (1.f / 131072.f);
  const float term = p * logf(p + 1e-10f);
  float s2 = wave_sum(term);
  if (lane == 0) red[w] = s2;
  __syncthreads();
  if (t == 0) {
    float a = 0.f;
#pragma unroll
    for (int i = 0; i < 8; ++i) a += red[i];
    out[8388609] = expf(-a);   // perplexity slot
  }
}

// ---------------------------------------------------------------------------
// K4: quantized gather + transposed write + commitment loss
// ---------------------------------------------------------------------------
__global__ __launch_bounds__(256, 4) void k_quant(
    const float* __restrict__ x_g, const int* __restrict__ idx_g,
    const float* __restrict__ nemb, float* __restrict__ out)
{
  float lsum = 0.f;
  const int stride = gridDim.x * 256;
  for (int i = blockIdx.x * 256 + threadIdx.x; i < (DIM * NTOT / 4); i += stride) {
    const int d = i >> 15;                 // / (NTOT/4)
    const int n4 = i & ((NTOT / 4) - 1);
    const float4 xv = *reinterpret_cast<const float4*>(x_g + ((size_t)d << 17) + 4 * n4);
    const int4 id = *reinterpret_cast<const int4*>(idx_g + 4 * n4);
    const float q0 = nemb[(id.x << 6) + d];
    const float q1 = nemb[(id.y << 6) + d];
    const float q2 = nemb[(id.z << 6) + d];
    const float q3 = nemb[(id.w << 6) + d];
    const float e0 = q0 - xv.x, e1 = q1 - xv.y, e2 = q2 - xv.z, e3 = q3 - xv.w;
    float* op = out + 1 + ((size_t)d << 17) + 4 * n4;   // quantized_st region
    op[0] = xv.x + e0;  // mimic x + (q - x) exactly
    op[1] = xv.y + e1;
    op[2] = xv.z + e2;
    op[3] = xv.w + e3;
    lsum += e0 * e0 + e1 * e1 + e2 * e2 + e3 * e3;
  }
  lsum = wave_sum(lsum);
  __shared__ float wsum[4];
  const int lane = threadIdx.x & 63, w = threadIdx.x >> 6;
  if (lane == 0) wsum[w] = lsum;
  __syncthreads();
  if (threadIdx.x == 0)
    unsafeAtomicAdd(out, (wsum[0] + wsum[1] + wsum[2] + wsum[3]) * (0.25f / 8388608.f));
}

// ---------------------------------------------------------------------------
extern "C" void kernel_launch(void* const* d_in, const int* in_sizes, int n_in,
                              void* d_out, int out_size, void* d_ws, size_t ws_size,
                              hipStream_t stream) {
  const float* x      = (const float*)d_in[0];   // [64][16][8192]
  const float* emb    = (const float*)d_in[1];   // [512][64]
  const float* ema_w  = (const float*)d_in[2];   // [512][64]
  const float* ema_cs = (const float*)d_in[3];   // [512]
  float* out = (float*)d_out;

  // d_out layout: loss@0 | q@1 (8388608) | perp@8388609 | enc@8388610 | dist@75497474
  float* enc_out  = out + 8388610;
  float* dist_out = out + 75497474;

  // ws layout: dw [512*64]f @0 | counts [512]u @131072 | new_emb @133120 | idx @264192
  char* ws = (char*)d_ws;
  float*    dw   = (float*)ws;
  unsigned* cnt  = (unsigned*)(ws + 131072);
  float*    nemb = (float*)(ws + 133120);
  int*      idx  = (int*)(ws + 264192);

  hipMemsetAsync(d_ws, 0, 133120, stream);          // zero dw + counts
  hipMemsetAsync(d_out, 0, sizeof(float), stream);  // zero loss accumulator

  k_dist<<<256, 512, 0, stream>>>(x, emb, dist_out, enc_out, idx, cnt, dw);
  k_final<<<1, 512, 0, stream>>>(ema_w, ema_cs, cnt, dw, nemb, out);
  k_quant<<<2048, 256, 0, stream>>>(x, idx, nemb, out);
}

// Round 13
// 347.831 us; speedup vs baseline: 1.1114x; 1.1114x over previous
//
#include <hip/hip_runtime.h>

#define NTOT 131072   // B*T
#define KCB  512
#define DIM  64

typedef __attribute__((ext_vector_type(8))) short bf16x8;
typedef __attribute__((ext_vector_type(4))) float f32x4;

__device__ __forceinline__ unsigned short f2bf(float f) {
  unsigned u = __float_as_uint(f);
  u = u + 0x7FFFu + ((u >> 16) & 1u);          // RNE
  return (unsigned short)(u >> 16);
}
__device__ __forceinline__ float bf2f(unsigned short h) {
  return __uint_as_float(((unsigned)h) << 16);
}
__device__ __forceinline__ float wave_sum(float v) {
#pragma unroll
  for (int off = 32; off; off >>= 1) v += __shfl_xor(v, off, 64);
  return v;
}

// ---------------------------------------------------------------------------
// K0: embsq = |e_k|^2 ; e' = -2e split into bf16 hi/lo tables [K][D]
// ---------------------------------------------------------------------------
__global__ __launch_bounds__(512, 1) void k_prep(
    const float* __restrict__ emb, unsigned short* __restrict__ eh,
    unsigned short* __restrict__ el, float* __restrict__ embsq)
{
  const int k = threadIdx.x;
  float sq = 0.f;
#pragma unroll 8
  for (int d = 0; d < DIM; ++d) {
    const float e = emb[k * DIM + d];
    sq = fmaf(e, e, sq);
    const float m = -2.f * e;
    const unsigned short h = f2bf(m);
    eh[k * DIM + d] = h;
    el[k * DIM + d] = f2bf(m - bf2f(h));
  }
  embsq[k] = sq;
}

// ---------------------------------------------------------------------------
// K1 (round 13 = round 12 resubmit): MFMA split-bf16 distance GEMM.
// 256 blocks x 512 thr (8 waves). Wave owns 64 rows; barrier-free.
// Per wave: stage rows as bf16 hi/lo in swizzled LDS; A-frags held in regs;
// loop 8 k-chunks of 64 codes: B-frags 16B from L2 tables, 6 MFMA per
// 16x16 tile (2 d-steps x {xh*eh, xh*el, xl*eh}); dist = acc + |x|^2 + |e|^2;
// packed running argmin; then idx/cnt/enc/dw epilogue.
// LDS: 128K xls + 2K xsq + 2K kmin = 132 KiB -> 1 block/CU.
// ---------------------------------------------------------------------------
__global__ __launch_bounds__(512, 2) void k_dist(
    const float* __restrict__ x_g,              // [D][N]
    const unsigned short* __restrict__ eh_g,    // [K][D] bf16 hi of -2e
    const unsigned short* __restrict__ el_g,    // [K][D] bf16 lo
    const float* __restrict__ embsq,            // [K]
    float* __restrict__ dist_out,               // [N][K]
    float* __restrict__ enc_out,                // [N][K]
    int* __restrict__ idx_out,                  // [N]
    unsigned* __restrict__ cnt_g,               // [K]
    float* __restrict__ dw_g)                   // [K][D]
{
  __shared__ unsigned short xls[8][2][64][64];  // [wave][hi/lo][row][d] swizzled
  __shared__ float xsq_l[8][64];
  __shared__ int   kmin_l[8][64];

  const int t = threadIdx.x;
  const int lane = t & 63;
  const int w = t >> 6;
  const int n0 = blockIdx.x * 512 + w * 64;     // wave's 64 rows

  // ---- stage: lane owns row n0+lane (coalesced over n per d)
  {
    float sq = 0.f;
#pragma unroll
    for (int half = 0; half < 2; ++half) {
      float v[32];
#pragma unroll
      for (int d = 0; d < 32; ++d)
        v[d] = x_g[(size_t)(half * 32 + d) * NTOT + n0 + lane];
#pragma unroll
      for (int d = 0; d < 32; ++d) {
        const float f = v[d];
        sq = fmaf(f, f, sq);
        const unsigned short h = f2bf(f);
        const unsigned short lo = f2bf(f - bf2f(h));
        const int dd = half * 32 + d;
        // 16B-chunk XOR swizzle: chunk' = (dd>>3) ^ (row&7)
        const int pos = ((((dd >> 3) ^ (lane & 7)) << 3) | (dd & 7));
        xls[w][0][lane][pos] = h;
        xls[w][1][lane][pos] = lo;
      }
    }
    xsq_l[w][lane] = sq;
  }
  asm volatile("" ::: "memory");   // wave-sync: staging before frag reads

  // ---- A-frags (x) held for whole kernel: [rowgroup][d-step][hi/lo]
  bf16x8 af[4][2][2];
#pragma unroll
  for (int rg = 0; rg < 4; ++rg) {
    const int row = rg * 16 + (lane & 15);
#pragma unroll
    for (int ds = 0; ds < 2; ++ds) {
      const int c = (ds * 4 + (lane >> 4)) ^ (row & 7);
#pragma unroll
      for (int hl = 0; hl < 2; ++hl)
        af[rg][ds][hl] =
            *reinterpret_cast<const bf16x8*>(&xls[w][hl][row][c << 3]);
    }
  }

  // ---- |x|^2 for this lane's 16 output rows (C layout: row=(l>>4)*4+j)
  float xsq_r[4][4];
#pragma unroll
  for (int rg = 0; rg < 4; ++rg)
#pragma unroll
    for (int j = 0; j < 4; ++j)
      xsq_r[rg][j] = xsq_l[w][rg * 16 + (lane >> 4) * 4 + j];

  unsigned long long mn[4][4];
#pragma unroll
  for (int rg = 0; rg < 4; ++rg)
#pragma unroll
    for (int j = 0; j < 4; ++j) mn[rg][j] = ~0ull;

  // ---- main loop over 8 k-chunks of 64 codes
  for (int kc = 0; kc < 8; ++kc) {
    const int kbase = kc * 64;
    f32x4 acc[4][4];
#pragma unroll
    for (int rg = 0; rg < 4; ++rg)
#pragma unroll
      for (int kg = 0; kg < 4; ++kg) acc[rg][kg] = (f32x4){0.f, 0.f, 0.f, 0.f};

#pragma unroll
    for (int kg = 0; kg < 4; ++kg) {
      const int kcode = kbase + kg * 16 + (lane & 15);
      const unsigned short* ph = eh_g + kcode * 64 + (lane >> 4) * 8;
      const unsigned short* pl = el_g + kcode * 64 + (lane >> 4) * 8;
      const bf16x8 beh0 = *reinterpret_cast<const bf16x8*>(ph);
      const bf16x8 beh1 = *reinterpret_cast<const bf16x8*>(ph + 32);
      const bf16x8 bel0 = *reinterpret_cast<const bf16x8*>(pl);
      const bf16x8 bel1 = *reinterpret_cast<const bf16x8*>(pl + 32);
#pragma unroll
      for (int rg = 0; rg < 4; ++rg) {
        f32x4 a = acc[rg][kg];
        a = __builtin_amdgcn_mfma_f32_16x16x32_bf16(af[rg][0][0], beh0, a, 0, 0, 0);
        a = __builtin_amdgcn_mfma_f32_16x16x32_bf16(af[rg][0][0], bel0, a, 0, 0, 0);
        a = __builtin_amdgcn_mfma_f32_16x16x32_bf16(af[rg][0][1], beh0, a, 0, 0, 0);
        a = __builtin_amdgcn_mfma_f32_16x16x32_bf16(af[rg][1][0], beh1, a, 0, 0, 0);
        a = __builtin_amdgcn_mfma_f32_16x16x32_bf16(af[rg][1][0], bel1, a, 0, 0, 0);
        a = __builtin_amdgcn_mfma_f32_16x16x32_bf16(af[rg][1][1], beh1, a, 0, 0, 0);
        acc[rg][kg] = a;
      }
    }

    // epilogue for this chunk: dist = acc + |x|^2 + |e|^2, store + running min
#pragma unroll
    for (int kg = 0; kg < 4; ++kg) {
      const unsigned kk0 = (unsigned)(kbase + kg * 16 + (lane & 15));
      const float eq = embsq[kk0];
#pragma unroll
      for (int rg = 0; rg < 4; ++rg) {
#pragma unroll
        for (int j = 0; j < 4; ++j) {
          const float dist = acc[rg][kg][j] + xsq_r[rg][j] + eq;
          dist_out[(size_t)(n0 + rg * 16 + (lane >> 4) * 4 + j) * KCB + kk0] = dist;
          const unsigned long long pk =
              ((unsigned long long)__float_as_uint(dist) << 32) | kk0;
          mn[rg][j] = pk < mn[rg][j] ? pk : mn[rg][j];
        }
      }
    }
  }

  // ---- reduce argmin across the 16 lanes sharing (lane>>4)
#pragma unroll
  for (int rg = 0; rg < 4; ++rg)
#pragma unroll
    for (int j = 0; j < 4; ++j) {
#pragma unroll
      for (int m = 1; m < 16; m <<= 1) {
        const unsigned long long o = __shfl_xor(mn[rg][j], m, 64);
        mn[rg][j] = o < mn[rg][j] ? o : mn[rg][j];
      }
    }
  if ((lane & 15) == 0) {
#pragma unroll
    for (int rg = 0; rg < 4; ++rg)
#pragma unroll
      for (int j = 0; j < 4; ++j)
        kmin_l[w][rg * 16 + (lane >> 4) * 4 + j] =
            (int)(mn[rg][j] & 0xFFFFFFFFull);
  }
  asm volatile("" ::: "memory");   // wave-sync: kmin visible to all lanes

  // ---- idx + cnt (lane owns row n0+lane)
  {
    const int km = kmin_l[w][lane];
    idx_out[n0 + lane] = km;
    atomicAdd(&cnt_g[km], 1u);
  }

  // ---- enc one-hot rows + dw scatter
  for (int r = 0; r < 64; ++r) {
    const int km = kmin_l[w][r];          // uniform (broadcast read)
    const int base = lane * 8;
    float4 z0, z1;
    z0.x = (km == base)     ? 1.f : 0.f;
    z0.y = (km == base + 1) ? 1.f : 0.f;
    z0.z = (km == base + 2) ? 1.f : 0.f;
    z0.w = (km == base + 3) ? 1.f : 0.f;
    z1.x = (km == base + 4) ? 1.f : 0.f;
    z1.y = (km == base + 5) ? 1.f : 0.f;
    z1.z = (km == base + 6) ? 1.f : 0.f;
    z1.w = (km == base + 7) ? 1.f : 0.f;
    float* ep = enc_out + (size_t)(n0 + r) * KCB + base;
    *reinterpret_cast<float4*>(ep) = z0;
    *reinterpret_cast<float4*>(ep + 4) = z1;

    // dw[km][d=lane] += x'(row r, d=lane)   (x' = hi+lo, same value MFMA saw)
    const int pos = ((((lane >> 3) ^ (r & 7)) << 3) | (lane & 7));
    const float xv = bf2f(xls[w][0][r][pos]) + bf2f(xls[w][1][r][pos]);
    unsafeAtomicAdd(dw_g + ((size_t)km << 6) + lane, xv);
  }
}

// ---------------------------------------------------------------------------
// K3: cluster EMA + laplace + new_emb + perplexity (1 block, 512 threads)
// ---------------------------------------------------------------------------
__global__ __launch_bounds__(512, 1) void k_final(
    const float* __restrict__ ema_w, const float* __restrict__ ema_cs,
    const unsigned* __restrict__ cnt, const float* __restrict__ dw,
    float* __restrict__ nemb, float* __restrict__ out)
{
  __shared__ float red[8];
  __shared__ float bc;
  const int t = threadIdx.x;
  const int lane = t & 63, w = t >> 6;

  const float c = (float)cnt[t];
  const float craw = ema_cs[t] * 0.99f + 0.01f * c;

  float s = wave_sum(craw);
  if (lane == 0) red[w] = s;
  __syncthreads();
  if (t == 0) {
    float a = 0.f;
#pragma unroll
    for (int i = 0; i < 8; ++i) a += red[i];
    bc = a;
  }
  __syncthreads();
  const float n = bc;
  const float clus = (craw + 1e-5f) / (n + 512.f * 1e-5f) * n;

  const float4* wr = reinterpret_cast<const float4*>(ema_w + t * 64);
  const float4* dr = reinterpret_cast<const float4*>(dw + t * 64);
  float4* nr = reinterpret_cast<float4*>(nemb + t * 64);
#pragma unroll
  for (int q = 0; q < 16; ++q) {
    const float4 wv = wr[q], dv = dr[q];
    float4 o;
    o.x = (wv.x * 0.99f + 0.01f * dv.x) / clus;
    o.y = (wv.y * 0.99f + 0.01f * dv.y) / clus;
    o.z = (wv.z * 0.99f + 0.01f * dv.z) / clus;
    o.w = (wv.w * 0.99f + 0.01f * dv.w) / clus;
    nr[q] = o;
  }

  const float p = c * (1.f / 131072.f);
  const float term = p * logf(p + 1e-10f);
  float s2 = wave_sum(term);
  if (lane == 0) red[w] = s2;
  __syncthreads();
  if (t == 0) {
    float a = 0.f;
#pragma unroll
    for (int i = 0; i < 8; ++i) a += red[i];
    out[8388609] = expf(-a);   // perplexity slot
  }
}

// ---------------------------------------------------------------------------
// K4: quantized gather + transposed write + commitment loss
// ---------------------------------------------------------------------------
__global__ __launch_bounds__(256, 4) void k_quant(
    const float* __restrict__ x_g, const int* __restrict__ idx_g,
    const float* __restrict__ nemb, float* __restrict__ out)
{
  float lsum = 0.f;
  const int stride = gridDim.x * 256;
  for (int i = blockIdx.x * 256 + threadIdx.x; i < (DIM * NTOT / 4); i += stride) {
    const int d = i >> 15;                 // / (NTOT/4)
    const int n4 = i & ((NTOT / 4) - 1);
    const float4 xv = *reinterpret_cast<const float4*>(x_g + ((size_t)d << 17) + 4 * n4);
    const int4 id = *reinterpret_cast<const int4*>(idx_g + 4 * n4);
    const float q0 = nemb[(id.x << 6) + d];
    const float q1 = nemb[(id.y << 6) + d];
    const float q2 = nemb[(id.z << 6) + d];
    const float q3 = nemb[(id.w << 6) + d];
    const float e0 = q0 - xv.x, e1 = q1 - xv.y, e2 = q2 - xv.z, e3 = q3 - xv.w;
    float* op = out + 1 + ((size_t)d << 17) + 4 * n4;   // quantized_st region
    op[0] = xv.x + e0;
    op[1] = xv.y + e1;
    op[2] = xv.z + e2;
    op[3] = xv.w + e3;
    lsum += e0 * e0 + e1 * e1 + e2 * e2 + e3 * e3;
  }
  lsum = wave_sum(lsum);
  __shared__ float wsum[4];
  const int lane = threadIdx.x & 63, w = threadIdx.x >> 6;
  if (lane == 0) wsum[w] = lsum;
  __syncthreads();
  if (threadIdx.x == 0)
    unsafeAtomicAdd(out, (wsum[0] + wsum[1] + wsum[2] + wsum[3]) * (0.25f / 8388608.f));
}

// ---------------------------------------------------------------------------
extern "C" void kernel_launch(void* const* d_in, const int* in_sizes, int n_in,
                              void* d_out, int out_size, void* d_ws, size_t ws_size,
                              hipStream_t stream) {
  const float* x      = (const float*)d_in[0];   // [64][16][8192]
  const float* emb    = (const float*)d_in[1];   // [512][64]
  const float* ema_w  = (const float*)d_in[2];   // [512][64]
  const float* ema_cs = (const float*)d_in[3];   // [512]
  float* out = (float*)d_out;

  // d_out: loss@0 | q@1 (8388608) | perp@8388609 | enc@8388610 | dist@75497474
  float* enc_out  = out + 8388610;
  float* dist_out = out + 75497474;

  // ws: dw@0 (131072) | cnt@131072 (2048) | nemb@133120 (131072) |
  //     idx@264192 (524288) | embsq@788480 (2048) | eh@790528 (65536) |
  //     el@856064 (65536)
  char* ws = (char*)d_ws;
  float*          dw    = (float*)ws;
  unsigned*       cnt   = (unsigned*)(ws + 131072);
  float*          nemb  = (float*)(ws + 133120);
  int*            idx   = (int*)(ws + 264192);
  float*          embsq = (float*)(ws + 788480);
  unsigned short* eh    = (unsigned short*)(ws + 790528);
  unsigned short* el    = (unsigned short*)(ws + 856064);

  hipMemsetAsync(d_ws, 0, 133120, stream);          // zero dw + counts
  hipMemsetAsync(d_out, 0, sizeof(float), stream);  // zero loss accumulator

  k_prep<<<1, 512, 0, stream>>>(emb, eh, el, embsq);
  k_dist<<<256, 512, 0, stream>>>(x, eh, el, embsq, dist_out, enc_out, idx, cnt, dw);
  k_final<<<1, 512, 0, stream>>>(ema_w, ema_cs, cnt, dw, nemb, out);
  k_quant<<<2048, 256, 0, stream>>>(x, idx, nemb, out);
}